// Round 5
// baseline (126.056 us; speedup 1.0000x reference)
//
#include <hip/hip_runtime.h>

#define THREADS 512
#define NBLK 512  // 65536 rows / 128 per block

typedef _Float16 half8 __attribute__((ext_vector_type(8)));
typedef float floatx4 __attribute__((ext_vector_type(4)));

// --- Kernel 1: W [512(k)][512(n)] fp32 -> Wt [512(n)][512(k)] f16 ---
__global__ void wcvt_kernel(const float* __restrict__ W, unsigned short* __restrict__ Wt) {
  __shared__ float tile[32][33];
  const int tx = threadIdx.x, ty = threadIdx.y;
  const int nb = blockIdx.x * 32, kb = blockIdx.y * 32;
#pragma unroll
  for (int i = 0; i < 4; ++i)
    tile[ty + 8 * i][tx] = W[(size_t)(kb + ty + 8 * i) * 512 + nb + tx];
  __syncthreads();
#pragma unroll
  for (int i = 0; i < 4; ++i) {
    union { _Float16 h; unsigned short u; } v;
    v.h = (_Float16)tile[tx][ty + 8 * i];
    Wt[(size_t)(nb + ty + 8 * i) * 512 + kb + tx] = v.u;
  }
}

// --- Kernel 2: fused GEMM + surrogate-sigmoid + rowwise LayerNorm ---
// Block tile: 128 rows x 512 cols, 8 waves (2 wrow x 4 wcol), wave tile 64x128.
// BK=64, 8 chunks. B: LDS double-buffer 2x64KB, all-DMA, counted vmcnt(8),
// refill only after post-MFMA barrier. A: direct global->VGPR fragments,
// prefetched one chunk ahead (no LDS, no barrier dependency).
// LDS: 2 x 65536 B for B; row R (0..511) at R*128, 8 slots x 16B,
// physical slot = logical ^ (R&7). Reductions alias after K-loop.
#define BBUF 65536

__global__ __launch_bounds__(THREADS, 2) void lif_fused_kernel(
    const float* __restrict__ A, const unsigned short* __restrict__ Wt,
    const float* __restrict__ bias, const float* __restrict__ lnw,
    const float* __restrict__ lnb, float* __restrict__ out) {
  __shared__ uint4 smem4[8192];  // 131072 bytes
  unsigned char* smem = (unsigned char*)smem4;

  const int tid  = threadIdx.x;
  const int lane = tid & 63;
  const int wave = tid >> 6;   // 0..7
  const int wrow = wave >> 2;  // 0..1
  const int wcol = wave & 3;   // 0..3
  const int l15  = lane & 15;
  const int g    = lane >> 4;  // 0..3
  const int rowBase = blockIdx.x * 128;

  // B staging: thread covers row (tid>>3), phys slot (tid&7) -> logical slot s.
  const int bs = (tid & 7) ^ ((tid >> 3) & 7);
  const unsigned short* bsrc = Wt + (size_t)(tid >> 3) * 512 + bs * 8;

  auto stageB = [&](int buf, int c) {
#pragma unroll
    for (int i = 0; i < 8; ++i) {  // 8 x (64 rows): 64 KB per chunk
      int off = buf * BBUF + i * 8192 + wave * 1024;
      off = __builtin_amdgcn_readfirstlane(off);
      __builtin_amdgcn_global_load_lds(
          (const __attribute__((address_space(1))) void*)(bsrc + i * 32768 + c * 64),
          (__attribute__((address_space(3))) void*)(smem + off), 16, 0, 0);
    }
  };

  // A fragment pointers: lane reads row (wrow*64 + m*16 + l15), k-base g*8.
  const float* ap[4];
#pragma unroll
  for (int m = 0; m < 4; ++m)
    ap[m] = A + (size_t)(rowBase + wrow * 64 + m * 16 + l15) * 512 + g * 8;

  // b-frag bases: row R = wcol*128 + n*16 + l15; logical slot ks*4+g.
  const int bByte0 = (wcol * 128 + l15) * 128 + ((g ^ (l15 & 7)) << 4);
  const int bByte1 = bByte0 ^ 64;  // ks=1: logical slot +4

  floatx4 acc[4][8];
#pragma unroll
  for (int m = 0; m < 4; ++m)
#pragma unroll
    for (int n = 0; n < 8; ++n)
      acc[m][n] = (floatx4){0.f, 0.f, 0.f, 0.f};

  float4 ar[4][2][2];  // in-flight A fp32 (statically indexed everywhere)

  // Prologue: A0 first (oldest), then B0, B1  -> vmcnt(8) at c=0 waits A0+B0.
#pragma unroll
  for (int m = 0; m < 4; ++m)
#pragma unroll
    for (int ks = 0; ks < 2; ++ks)
#pragma unroll
      for (int h = 0; h < 2; ++h)
        ar[m][ks][h] = *(const float4*)(ap[m] + ks * 32 + h * 4);
  stageB(0, 0);
  stageB(1, 1);

#pragma unroll
  for (int c = 0; c < 8; ++c) {
    if (c < 7) {
      asm volatile("s_waitcnt vmcnt(8)" ::: "memory");  // B_c + A_c landed
    } else {
      asm volatile("s_waitcnt vmcnt(0)" ::: "memory");
    }
    __builtin_amdgcn_s_barrier();
    __builtin_amdgcn_sched_barrier(0);

    const int buf = c & 1;
    const unsigned char* bb0 = smem + buf * BBUF + bByte0;
    const unsigned char* bb1 = smem + buf * BBUF + bByte1;

#pragma unroll
    for (int ks = 0; ks < 2; ++ks) {
      // Convert this ks-half fp32 -> f16 fragments (frees ar[*][ks][*]).
      half8 a0, a1, a2, a3;
      {
        half8 t;
        float4 lo, hi;
        lo = ar[0][ks][0]; hi = ar[0][ks][1];
        t[0]=(_Float16)lo.x; t[1]=(_Float16)lo.y; t[2]=(_Float16)lo.z; t[3]=(_Float16)lo.w;
        t[4]=(_Float16)hi.x; t[5]=(_Float16)hi.y; t[6]=(_Float16)hi.z; t[7]=(_Float16)hi.w;
        a0 = t;
        lo = ar[1][ks][0]; hi = ar[1][ks][1];
        t[0]=(_Float16)lo.x; t[1]=(_Float16)lo.y; t[2]=(_Float16)lo.z; t[3]=(_Float16)lo.w;
        t[4]=(_Float16)hi.x; t[5]=(_Float16)hi.y; t[6]=(_Float16)hi.z; t[7]=(_Float16)hi.w;
        a1 = t;
        lo = ar[2][ks][0]; hi = ar[2][ks][1];
        t[0]=(_Float16)lo.x; t[1]=(_Float16)lo.y; t[2]=(_Float16)lo.z; t[3]=(_Float16)lo.w;
        t[4]=(_Float16)hi.x; t[5]=(_Float16)hi.y; t[6]=(_Float16)hi.z; t[7]=(_Float16)hi.w;
        a2 = t;
        lo = ar[3][ks][0]; hi = ar[3][ks][1];
        t[0]=(_Float16)lo.x; t[1]=(_Float16)lo.y; t[2]=(_Float16)lo.z; t[3]=(_Float16)lo.w;
        t[4]=(_Float16)hi.x; t[5]=(_Float16)hi.y; t[6]=(_Float16)hi.z; t[7]=(_Float16)hi.w;
        a3 = t;
      }
      // Prefetch next chunk's same ks-half into the freed registers.
      if (c < 7) {
#pragma unroll
        for (int m = 0; m < 4; ++m)
#pragma unroll
          for (int h = 0; h < 2; ++h)
            ar[m][ks][h] = *(const float4*)(ap[m] + (c + 1) * 64 + ks * 32 + h * 4);
      }
      const unsigned char* bb = (ks == 0) ? bb0 : bb1;
      __builtin_amdgcn_s_setprio(1);
#pragma unroll
      for (int n = 0; n < 8; ++n) {
        half8 bf = *(const half8*)(bb + n * 2048);
        acc[0][n] = __builtin_amdgcn_mfma_f32_16x16x32_f16(a0, bf, acc[0][n], 0, 0, 0);
        acc[1][n] = __builtin_amdgcn_mfma_f32_16x16x32_f16(a1, bf, acc[1][n], 0, 0, 0);
        acc[2][n] = __builtin_amdgcn_mfma_f32_16x16x32_f16(a2, bf, acc[2][n], 0, 0, 0);
        acc[3][n] = __builtin_amdgcn_mfma_f32_16x16x32_f16(a3, bf, acc[3][n], 0, 0, 0);
      }
      __builtin_amdgcn_s_setprio(0);
    }

    __builtin_amdgcn_sched_barrier(0);
    // All waves consumed buf's fragments into registers -> safe to refill.
    __builtin_amdgcn_s_barrier();
    __builtin_amdgcn_sched_barrier(0);
    if (c < 6) stageB(buf, c + 2);
  }
  __syncthreads();

  // --- Epilogue: bias + surrogate spike + fused LayerNorm ---
  float bcol[8], lsc[8], lbc[8];
#pragma unroll
  for (int n = 0; n < 8; ++n) {
    const int col = wcol * 128 + n * 16 + l15;
    bcol[n] = bias[col];
    lsc[n]  = lnw[col];
    lbc[n]  = lnb[col];
  }
#pragma unroll
  for (int m = 0; m < 4; ++m)
#pragma unroll
    for (int n = 0; n < 8; ++n)
#pragma unroll
      for (int r = 0; r < 4; ++r) {
        // alpha=exp(-50): v == current in fp32; spike = fast_sigmoid(v - 0.5, 4)
        float x  = acc[m][n][r] + bcol[n] - 0.5f;
        float bx = 4.0f * x;
        acc[m][n][r] = 0.5f * bx / (1.0f + fabsf(bx)) + 0.5f;
      }

  float rs[4][4], rq[4][4];
#pragma unroll
  for (int m = 0; m < 4; ++m)
#pragma unroll
    for (int r = 0; r < 4; ++r) {
      float s = 0.f, q = 0.f;
#pragma unroll
      for (int n = 0; n < 8; ++n) {
        float v = acc[m][n][r];
        s += v;
        q += v * v;
      }
      rs[m][r] = s;
      rq[m][r] = q;
    }
#pragma unroll
  for (int d = 1; d < 16; d <<= 1) {
#pragma unroll
    for (int m = 0; m < 4; ++m)
#pragma unroll
      for (int r = 0; r < 4; ++r) {
        rs[m][r] += __shfl_xor(rs[m][r], d, 16);
        rq[m][r] += __shfl_xor(rq[m][r], d, 16);
      }
  }

  float* redS = (float*)smem4;   // [128][4]
  float* redQ = redS + 512;      // [128][4]
  float* mv   = redQ + 512;      // [128][2]
  if (l15 == 0) {
#pragma unroll
    for (int m = 0; m < 4; ++m)
#pragma unroll
      for (int r = 0; r < 4; ++r) {
        const int row = wrow * 64 + m * 16 + g * 4 + r;
        redS[row * 4 + wcol] = rs[m][r];
        redQ[row * 4 + wcol] = rq[m][r];
      }
  }
  __syncthreads();
  if (tid < 128) {
    const float S = redS[tid * 4] + redS[tid * 4 + 1] + redS[tid * 4 + 2] + redS[tid * 4 + 3];
    const float Q = redQ[tid * 4] + redQ[tid * 4 + 1] + redQ[tid * 4 + 2] + redQ[tid * 4 + 3];
    const float mean = S * (1.0f / 512.0f);
    const float var  = Q * (1.0f / 512.0f) - mean * mean;
    mv[tid * 2]     = mean;
    mv[tid * 2 + 1] = rsqrtf(var + 1e-6f);
  }
  __syncthreads();

#pragma unroll
  for (int m = 0; m < 4; ++m)
#pragma unroll
    for (int r = 0; r < 4; ++r) {
      const int row  = wrow * 64 + m * 16 + g * 4 + r;
      const float mean = mv[row * 2];
      const float rstd = mv[row * 2 + 1];
      const size_t base = (size_t)(rowBase + row) * 512;
#pragma unroll
      for (int n = 0; n < 8; ++n) {
        const int col = wcol * 128 + n * 16 + l15;
        out[base + col] = (acc[m][n][r] - mean) * rstd * lsc[n] + lbc[n];
      }
    }
}

extern "C" void kernel_launch(void* const* d_in, const int* in_sizes, int n_in,
                              void* d_out, int out_size, void* d_ws, size_t ws_size,
                              hipStream_t stream) {
  const float* spikes = (const float*)d_in[0];
  const float* W      = (const float*)d_in[1];
  const float* b      = (const float*)d_in[2];
  const float* lnw    = (const float*)d_in[3];
  const float* lnb    = (const float*)d_in[4];
  float* out = (float*)d_out;
  unsigned short* Wt = (unsigned short*)d_ws;  // 512*512*2 = 512 KB scratch

  wcvt_kernel<<<dim3(16, 16), dim3(32, 8), 0, stream>>>(W, Wt);
  lif_fused_kernel<<<NBLK, THREADS, 0, stream>>>(spikes, Wt, b, lnw, lnb, out);
}

// Round 6
// 95.391 us; speedup vs baseline: 1.3215x; 1.3215x over previous
//
#include <hip/hip_runtime.h>

#define THREADS 512
#define NBLK 512  // 65536 rows / 128 per block

typedef _Float16 half8 __attribute__((ext_vector_type(8)));
typedef float floatx4 __attribute__((ext_vector_type(4)));

// --- Kernel 1: W [512(k)][512(n)] fp32 -> Wt [512(n)][512(k)] f16 ---
__global__ void wcvt_kernel(const float* __restrict__ W, unsigned short* __restrict__ Wt) {
  __shared__ float tile[32][33];
  const int tx = threadIdx.x, ty = threadIdx.y;
  const int nb = blockIdx.x * 32, kb = blockIdx.y * 32;
#pragma unroll
  for (int i = 0; i < 4; ++i)
    tile[ty + 8 * i][tx] = W[(size_t)(kb + ty + 8 * i) * 512 + nb + tx];
  __syncthreads();
#pragma unroll
  for (int i = 0; i < 4; ++i) {
    union { _Float16 h; unsigned short u; } v;
    v.h = (_Float16)tile[tx][ty + 8 * i];
    Wt[(size_t)(nb + ty + 8 * i) * 512 + kb + tx] = v.u;
  }
}

// --- Kernel 2: fused GEMM + surrogate-sigmoid + rowwise LayerNorm ---
// Block: 128 rows x 512 cols, 8 waves (2 wrow x 4 wcol), wave tile 64x128.
// BK=32, 16 chunks. Per chunk per thread: 4 B-DMA + 2 A-glb + 1 ds_write +
// 12 ds_read_b128 + 32 MFMA. One barrier per chunk; stage targets the OTHER
// buffer, issued at the very top of the chunk (max issue->wait distance so the
// end-of-chunk vmcnt(0) finds everything landed). A converted fp32->f16 in
// registers (T14 split: load top, cvt+write bottom).
// LDS (bytes): A f16 [0,16384) 2 x 8192 (128r x 4 slots x 16B, XOR-swizzled)
//              B f16 [16384,81920) 2 x 32768 (512n x 4 slots x 16B, swizzled)
// Reduction scratch aliases A region after the K-loop.
#define ABUF 8192
#define BBASE 16384
#define BBUF 32768

__global__ __launch_bounds__(THREADS, 2) void lif_fused_kernel(
    const float* __restrict__ A, const unsigned short* __restrict__ Wt,
    const float* __restrict__ bias, const float* __restrict__ lnw,
    const float* __restrict__ lnb, float* __restrict__ out) {
  __shared__ uint4 smem4[5120];  // 81920 bytes
  unsigned char* smem = (unsigned char*)smem4;

  const int tid  = threadIdx.x;
  const int lane = tid & 63;
  const int wave = tid >> 6;   // 0..7
  const int wrow = wave >> 2;  // 0..1
  const int wcol = wave & 3;   // 0..3
  const int l15  = lane & 15;
  const int g    = lane >> 4;  // 0..3
  const int rowBase = blockIdx.x * 128;

  // B staging: for i in 0..3, thread covers row n = i*128 + (tid>>2), phys
  // slot p = tid&3; logical slot s_b = p ^ (n&3) ^ ((n>>2)&3) (i-independent).
  const int s_b = (tid & 3) ^ ((tid >> 2) & 3) ^ ((tid >> 4) & 3);
  const unsigned short* bsrc = Wt + (size_t)(tid >> 2) * 512 + s_b * 8;

  // A staging: thread covers row r_a = tid>>2 (0..127), logical slot tid&3.
  const int r_a = tid >> 2;
  const int s_a = tid & 3;
  const float* asrc = A + (size_t)(rowBase + r_a) * 512 + s_a * 8;
  const int aPhys = s_a ^ (r_a & 3) ^ ((r_a >> 2) & 3);
  const int aWByte = r_a * 64 + aPhys * 16;  // + buf*ABUF

  auto stageB = [&](int buf, int c) {
#pragma unroll
    for (int i = 0; i < 4; ++i) {
      int off = BBASE + buf * BBUF + i * 8192 + wave * 1024;
      off = __builtin_amdgcn_readfirstlane(off);
      __builtin_amdgcn_global_load_lds(
          (const __attribute__((address_space(1))) void*)(bsrc + (size_t)i * 65536 + c * 32),
          (__attribute__((address_space(3))) void*)(smem + off), 16, 0, 0);
    }
  };

  // Fragment read bases (2-way bank alias max = free).
  const int sw  = g ^ (l15 & 3) ^ ((l15 >> 2) & 3);
  const int aRB = (wrow * 64 + l15) * 64 + sw * 16;           // + m*1024 + buf*ABUF
  const int bRB = BBASE + (wcol * 128 + l15) * 64 + sw * 16;  // + n*1024 + buf*BBUF

  floatx4 acc[4][8];
#pragma unroll
  for (int m = 0; m < 4; ++m)
#pragma unroll
    for (int n = 0; n < 8; ++n)
      acc[m][n] = (floatx4){0.f, 0.f, 0.f, 0.f};

  float4 ar0, ar1;
  auto loadA = [&](int c) {
    ar0 = *(const float4*)(asrc + c * 32);
    ar1 = *(const float4*)(asrc + c * 32 + 4);
  };
  auto writeA = [&](int buf) {
    half8 t;
    t[0] = (_Float16)ar0.x; t[1] = (_Float16)ar0.y;
    t[2] = (_Float16)ar0.z; t[3] = (_Float16)ar0.w;
    t[4] = (_Float16)ar1.x; t[5] = (_Float16)ar1.y;
    t[6] = (_Float16)ar1.z; t[7] = (_Float16)ar1.w;
    *(half8*)(smem + buf * ABUF + aWByte) = t;
  };

  // Prologue: stage chunk 0 into buffer 0.
  loadA(0);
  stageB(0, 0);
  writeA(0);  // compiler inserts the vmcnt for ar use
  asm volatile("s_waitcnt vmcnt(0) lgkmcnt(0)" ::: "memory");
  __builtin_amdgcn_s_barrier();
  __builtin_amdgcn_sched_barrier(0);

#pragma unroll
  for (int c = 0; c < 16; ++c) {
    const int buf = c & 1;
    // Issue next chunk's staging FIRST (into the other buffer -> no race).
    if (c < 15) {
      loadA(c + 1);
      stageB(buf ^ 1, c + 1);
    }
    // Compute on current buffer.
    half8 a0 = *(const half8*)(smem + buf * ABUF + aRB);
    half8 a1 = *(const half8*)(smem + buf * ABUF + aRB + 1024);
    half8 a2 = *(const half8*)(smem + buf * ABUF + aRB + 2048);
    half8 a3 = *(const half8*)(smem + buf * ABUF + aRB + 3072);
    const unsigned char* bb = smem + buf * BBUF + bRB;
    __builtin_amdgcn_s_setprio(1);
#pragma unroll
    for (int n = 0; n < 8; ++n) {
      half8 bf = *(const half8*)(bb + n * 1024);
      acc[0][n] = __builtin_amdgcn_mfma_f32_16x16x32_f16(a0, bf, acc[0][n], 0, 0, 0);
      acc[1][n] = __builtin_amdgcn_mfma_f32_16x16x32_f16(a1, bf, acc[1][n], 0, 0, 0);
      acc[2][n] = __builtin_amdgcn_mfma_f32_16x16x32_f16(a2, bf, acc[2][n], 0, 0, 0);
      acc[3][n] = __builtin_amdgcn_mfma_f32_16x16x32_f16(a3, bf, acc[3][n], 0, 0, 0);
    }
    __builtin_amdgcn_s_setprio(0);
    __builtin_amdgcn_sched_barrier(0);
    if (c < 15) {
      writeA(buf ^ 1);  // cvt + ds_write (compiler waits the A-glb regs)
      asm volatile("s_waitcnt vmcnt(0) lgkmcnt(0)" ::: "memory");
      __builtin_amdgcn_s_barrier();
      __builtin_amdgcn_sched_barrier(0);
    }
  }
  __syncthreads();

  // --- Epilogue: bias + surrogate spike + fused LayerNorm ---
  float bcol[8], lsc[8], lbc[8];
#pragma unroll
  for (int n = 0; n < 8; ++n) {
    const int col = wcol * 128 + n * 16 + l15;
    bcol[n] = bias[col];
    lsc[n]  = lnw[col];
    lbc[n]  = lnb[col];
  }
#pragma unroll
  for (int m = 0; m < 4; ++m)
#pragma unroll
    for (int n = 0; n < 8; ++n)
#pragma unroll
      for (int r = 0; r < 4; ++r) {
        // alpha=exp(-50): v == current in fp32; spike = fast_sigmoid(v - 0.5, 4)
        float x  = acc[m][n][r] + bcol[n] - 0.5f;
        float bx = 4.0f * x;
        acc[m][n][r] = 0.5f * bx / (1.0f + fabsf(bx)) + 0.5f;
      }

  float rs[4][4], rq[4][4];
#pragma unroll
  for (int m = 0; m < 4; ++m)
#pragma unroll
    for (int r = 0; r < 4; ++r) {
      float s = 0.f, q = 0.f;
#pragma unroll
      for (int n = 0; n < 8; ++n) {
        float v = acc[m][n][r];
        s += v;
        q += v * v;
      }
      rs[m][r] = s;
      rq[m][r] = q;
    }
#pragma unroll
  for (int d = 1; d < 16; d <<= 1) {
#pragma unroll
    for (int m = 0; m < 4; ++m)
#pragma unroll
      for (int r = 0; r < 4; ++r) {
        rs[m][r] += __shfl_xor(rs[m][r], d, 16);
        rq[m][r] += __shfl_xor(rq[m][r], d, 16);
      }
  }

  float* redS = (float*)smem4;   // [128][4]
  float* redQ = redS + 512;      // [128][4]
  float* mv   = redQ + 512;      // [128][2]
  if (l15 == 0) {
#pragma unroll
    for (int m = 0; m < 4; ++m)
#pragma unroll
      for (int r = 0; r < 4; ++r) {
        const int row = wrow * 64 + m * 16 + g * 4 + r;
        redS[row * 4 + wcol] = rs[m][r];
        redQ[row * 4 + wcol] = rq[m][r];
      }
  }
  __syncthreads();
  if (tid < 128) {
    const float S = redS[tid * 4] + redS[tid * 4 + 1] + redS[tid * 4 + 2] + redS[tid * 4 + 3];
    const float Q = redQ[tid * 4] + redQ[tid * 4 + 1] + redQ[tid * 4 + 2] + redQ[tid * 4 + 3];
    const float mean = S * (1.0f / 512.0f);
    const float var  = Q * (1.0f / 512.0f) - mean * mean;
    mv[tid * 2]     = mean;
    mv[tid * 2 + 1] = rsqrtf(var + 1e-6f);
  }
  __syncthreads();

#pragma unroll
  for (int m = 0; m < 4; ++m)
#pragma unroll
    for (int r = 0; r < 4; ++r) {
      const int row  = wrow * 64 + m * 16 + g * 4 + r;
      const float mean = mv[row * 2];
      const float rstd = mv[row * 2 + 1];
      const size_t base = (size_t)(rowBase + row) * 512;
#pragma unroll
      for (int n = 0; n < 8; ++n) {
        const int col = wcol * 128 + n * 16 + l15;
        out[base + col] = (acc[m][n][r] - mean) * rstd * lsc[n] + lbc[n];
      }
    }
}

extern "C" void kernel_launch(void* const* d_in, const int* in_sizes, int n_in,
                              void* d_out, int out_size, void* d_ws, size_t ws_size,
                              hipStream_t stream) {
  const float* spikes = (const float*)d_in[0];
  const float* W      = (const float*)d_in[1];
  const float* b      = (const float*)d_in[2];
  const float* lnw    = (const float*)d_in[3];
  const float* lnb    = (const float*)d_in[4];
  float* out = (float*)d_out;
  unsigned short* Wt = (unsigned short*)d_ws;  // 512*512*2 = 512 KB scratch

  wcvt_kernel<<<dim3(16, 16), dim3(32, 8), 0, stream>>>(W, Wt);
  lif_fused_kernel<<<NBLK, THREADS, 0, stream>>>(spikes, Wt, b, lnw, lnb, out);
}

// Round 7
// 91.485 us; speedup vs baseline: 1.3779x; 1.0427x over previous
//
#include <hip/hip_runtime.h>

#define THREADS 512
#define NBLK 1024  // 65536 rows / 64 per block

typedef _Float16 half8 __attribute__((ext_vector_type(8)));
typedef float floatx4 __attribute__((ext_vector_type(4)));

// --- Kernel 1: W [512(k)][512(n)] fp32 -> Wt [512(n)][512(k)] f16 ---
__global__ void wcvt_kernel(const float* __restrict__ W, unsigned short* __restrict__ Wt) {
  __shared__ float tile[32][33];
  const int tx = threadIdx.x, ty = threadIdx.y;
  const int nb = blockIdx.x * 32, kb = blockIdx.y * 32;
#pragma unroll
  for (int i = 0; i < 4; ++i)
    tile[ty + 8 * i][tx] = W[(size_t)(kb + ty + 8 * i) * 512 + nb + tx];
  __syncthreads();
#pragma unroll
  for (int i = 0; i < 4; ++i) {
    union { _Float16 h; unsigned short u; } v;
    v.h = (_Float16)tile[tx][ty + 8 * i];
    Wt[(size_t)(nb + ty + 8 * i) * 512 + kb + tx] = v.u;
  }
}

// --- Kernel 2: fused GEMM + surrogate-sigmoid + rowwise LayerNorm ---
// Register-budget-first: acc[2][8]=64 AGPR, body <=64 VGPR, launch_bounds(512,4)
// -> 16 waves/CU = 2 resident 8-wave blocks. Phase-alternating schedule:
//   compute(c) -> barrier -> stage(c+1) -> vmcnt(0) -> barrier
// stage phase (pure DMA) of one block overlaps compute phase (pure LDS/MFMA)
// of the sibling block. Single-buffered A and B (refill only after the
// post-compute barrier -> race-free).
// Block tile 64 x 512, 8 waves (2 wrow x 4 wcol), wave tile 32x128. BK=64.
// LDS: A fp32 [0,16384): 64 rows x 16 slots x 16B, phys slot = logical^(row&15)
//      B f16 [16384,81920): 512 rows x 8 slots x 16B, phys = logical^(row&7)
// Reduction scratch aliases the A region after the K-loop.
#define BBASE 16384

__global__ __launch_bounds__(THREADS, 4) void lif_fused_kernel(
    const float* __restrict__ A, const unsigned short* __restrict__ Wt,
    const float* __restrict__ bias, const float* __restrict__ lnw,
    const float* __restrict__ lnb, float* __restrict__ out) {
  __shared__ uint4 smem4[5120];  // 81920 bytes
  unsigned char* smem = (unsigned char*)smem4;

  const int tid  = threadIdx.x;
  const int lane = tid & 63;
  const int wave = tid >> 6;   // 0..7
  const int wrow = wave >> 2;  // 0..1
  const int wcol = wave & 3;   // 0..3
  const int l15  = lane & 15;
  const int g    = lane >> 4;  // 0..3
  const int rowBase = blockIdx.x * 64;

  // --- staging source addresses (inverse-swizzled global, linear LDS dest) ---
  // A: DMA j covers rows j*32 + wave*4 + (lane>>4); 32%16==0 so swizzle slot
  // is j-independent.
  const int arow  = wave * 4 + (lane >> 4);
  const int aslot = (lane & 15) ^ (arow & 15);
  const float* asrcA = A + (size_t)(rowBase + arow) * 512 + aslot * 4;
  // B: DMA i covers rows i*64 + wave*8 + (lane>>3); i*64,wave*8 % 8 == 0.
  const unsigned short* bsrcB =
      Wt + (size_t)(wave * 8 + (lane >> 3)) * 512 + ((lane & 7) ^ (lane >> 3)) * 8;

  auto stage = [&](int c) {
#pragma unroll
    for (int j = 0; j < 2; ++j) {  // A fp32: 2 x 8 KB
      int off = j * 8192 + wave * 1024;
      off = __builtin_amdgcn_readfirstlane(off);
      __builtin_amdgcn_global_load_lds(
          (const __attribute__((address_space(1))) void*)(asrcA + (size_t)j * 16384 + c * 64),
          (__attribute__((address_space(3))) void*)(smem + off), 16, 0, 0);
    }
#pragma unroll
    for (int i = 0; i < 8; ++i) {  // B f16: 8 x 8 KB
      int off = BBASE + i * 8192 + wave * 1024;
      off = __builtin_amdgcn_readfirstlane(off);
      __builtin_amdgcn_global_load_lds(
          (const __attribute__((address_space(1))) void*)(bsrcB + (size_t)i * 32768 + c * 64),
          (__attribute__((address_space(3))) void*)(smem + off), 16, 0, 0);
    }
  };

  // --- fragment read addresses ---
  // A (fp32): row = wrow*32 + m*16 + l15 (row&15 == l15); logical slot pair
  // for (ks,g) = {ks*8+g*2, +1}; phys = logical ^ l15.
  const int aRowB = (wrow * 32 + l15) * 256;
  const int e0 = (g * 2) ^ l15;  // 0..15
  const unsigned char* aP00 = smem + aRowB + e0 * 16;          // ks0 lo
  const unsigned char* aP01 = smem + aRowB + (e0 ^ 1) * 16;    // ks0 hi
  const unsigned char* aP10 = smem + aRowB + (e0 ^ 8) * 16;    // ks1 lo
  const unsigned char* aP11 = smem + aRowB + (e0 ^ 9) * 16;    // ks1 hi
  // B (f16): row = wcol*128 + n*16 + l15 (row&7 == l15&7); logical slot ks*4+g.
  const int bRowB = BBASE + (wcol * 128 + l15) * 128;
  const int f0 = g ^ (l15 & 7);
  const unsigned char* bP0 = smem + bRowB + f0 * 16;        // ks0, + n*2048
  const unsigned char* bP1 = smem + bRowB + (f0 ^ 4) * 16;  // ks1, + n*2048

  floatx4 acc[2][8];
#pragma unroll
  for (int m = 0; m < 2; ++m)
#pragma unroll
    for (int n = 0; n < 8; ++n)
      acc[m][n] = (floatx4){0.f, 0.f, 0.f, 0.f};

  auto mk = [](float4 lo, float4 hi) {
    half8 t;
    t[0] = (_Float16)lo.x; t[1] = (_Float16)lo.y;
    t[2] = (_Float16)lo.z; t[3] = (_Float16)lo.w;
    t[4] = (_Float16)hi.x; t[5] = (_Float16)hi.y;
    t[6] = (_Float16)hi.z; t[7] = (_Float16)hi.w;
    return t;
  };

  auto compute = [&]() {
    {  // ks = 0
      half8 a0 = mk(*(const float4*)aP00, *(const float4*)aP01);
      half8 a1 = mk(*(const float4*)(aP00 + 4096), *(const float4*)(aP01 + 4096));
      __builtin_amdgcn_s_setprio(1);
#pragma unroll
      for (int n = 0; n < 8; ++n) {
        half8 bf = *(const half8*)(bP0 + n * 2048);
        acc[0][n] = __builtin_amdgcn_mfma_f32_16x16x32_f16(a0, bf, acc[0][n], 0, 0, 0);
        acc[1][n] = __builtin_amdgcn_mfma_f32_16x16x32_f16(a1, bf, acc[1][n], 0, 0, 0);
      }
      __builtin_amdgcn_s_setprio(0);
    }
    {  // ks = 1
      half8 a0 = mk(*(const float4*)aP10, *(const float4*)aP11);
      half8 a1 = mk(*(const float4*)(aP10 + 4096), *(const float4*)(aP11 + 4096));
      __builtin_amdgcn_s_setprio(1);
#pragma unroll
      for (int n = 0; n < 8; ++n) {
        half8 bf = *(const half8*)(bP1 + n * 2048);
        acc[0][n] = __builtin_amdgcn_mfma_f32_16x16x32_f16(a0, bf, acc[0][n], 0, 0, 0);
        acc[1][n] = __builtin_amdgcn_mfma_f32_16x16x32_f16(a1, bf, acc[1][n], 0, 0, 0);
      }
      __builtin_amdgcn_s_setprio(0);
    }
  };

  // Prologue: fill buffers with chunk 0.
  stage(0);
  asm volatile("s_waitcnt vmcnt(0)" ::: "memory");
  __builtin_amdgcn_s_barrier();
  __builtin_amdgcn_sched_barrier(0);

#pragma unroll 1
  for (int c = 0; c < 7; ++c) {
    compute();  // reads chunk c from LDS
    __builtin_amdgcn_sched_barrier(0);
    __builtin_amdgcn_s_barrier();  // all waves done reading -> safe to refill
    __builtin_amdgcn_sched_barrier(0);
    stage(c + 1);
    asm volatile("s_waitcnt vmcnt(0)" ::: "memory");  // own DMAs landed
    __builtin_amdgcn_s_barrier();                     // everyone's landed
    __builtin_amdgcn_sched_barrier(0);
  }
  compute();  // chunk 7
  __syncthreads();

  // --- Epilogue: bias + surrogate spike + fused LayerNorm ---
  float bcol[8], lsc[8], lbc[8];
#pragma unroll
  for (int n = 0; n < 8; ++n) {
    const int col = wcol * 128 + n * 16 + l15;
    bcol[n] = bias[col];
    lsc[n]  = lnw[col];
    lbc[n]  = lnb[col];
  }
#pragma unroll
  for (int m = 0; m < 2; ++m)
#pragma unroll
    for (int n = 0; n < 8; ++n)
#pragma unroll
      for (int r = 0; r < 4; ++r) {
        // alpha=exp(-50): v == current in fp32; spike = fast_sigmoid(v - 0.5, 4)
        float x  = acc[m][n][r] + bcol[n] - 0.5f;
        float bx = 4.0f * x;
        acc[m][n][r] = 0.5f * bx / (1.0f + fabsf(bx)) + 0.5f;
      }

  float rs[2][4], rq[2][4];
#pragma unroll
  for (int m = 0; m < 2; ++m)
#pragma unroll
    for (int r = 0; r < 4; ++r) {
      float s = 0.f, q = 0.f;
#pragma unroll
      for (int n = 0; n < 8; ++n) {
        float v = acc[m][n][r];
        s += v;
        q += v * v;
      }
      rs[m][r] = s;
      rq[m][r] = q;
    }
#pragma unroll
  for (int d = 1; d < 16; d <<= 1) {
#pragma unroll
    for (int m = 0; m < 2; ++m)
#pragma unroll
      for (int r = 0; r < 4; ++r) {
        rs[m][r] += __shfl_xor(rs[m][r], d, 16);
        rq[m][r] += __shfl_xor(rq[m][r], d, 16);
      }
  }

  float* redS = (float*)smem4;   // [64][4]
  float* redQ = redS + 256;      // [64][4]
  float* mv   = redQ + 256;      // [64][2]
  if (l15 == 0) {
#pragma unroll
    for (int m = 0; m < 2; ++m)
#pragma unroll
      for (int r = 0; r < 4; ++r) {
        const int row = wrow * 32 + m * 16 + g * 4 + r;
        redS[row * 4 + wcol] = rs[m][r];
        redQ[row * 4 + wcol] = rq[m][r];
      }
  }
  __syncthreads();
  if (tid < 64) {
    const float S = redS[tid * 4] + redS[tid * 4 + 1] + redS[tid * 4 + 2] + redS[tid * 4 + 3];
    const float Q = redQ[tid * 4] + redQ[tid * 4 + 1] + redQ[tid * 4 + 2] + redQ[tid * 4 + 3];
    const float mean = S * (1.0f / 512.0f);
    const float var  = Q * (1.0f / 512.0f) - mean * mean;
    mv[tid * 2]     = mean;
    mv[tid * 2 + 1] = rsqrtf(var + 1e-6f);
  }
  __syncthreads();

#pragma unroll
  for (int m = 0; m < 2; ++m)
#pragma unroll
    for (int r = 0; r < 4; ++r) {
      const int row  = wrow * 32 + m * 16 + g * 4 + r;
      const float mean = mv[row * 2];
      const float rstd = mv[row * 2 + 1];
      const size_t base = (size_t)(rowBase + row) * 512;
#pragma unroll
      for (int n = 0; n < 8; ++n) {
        const int col = wcol * 128 + n * 16 + l15;
        out[base + col] = (acc[m][n][r] - mean) * rstd * lsc[n] + lbc[n];
      }
    }
}

extern "C" void kernel_launch(void* const* d_in, const int* in_sizes, int n_in,
                              void* d_out, int out_size, void* d_ws, size_t ws_size,
                              hipStream_t stream) {
  const float* spikes = (const float*)d_in[0];
  const float* W      = (const float*)d_in[1];
  const float* b      = (const float*)d_in[2];
  const float* lnw    = (const float*)d_in[3];
  const float* lnb    = (const float*)d_in[4];
  float* out = (float*)d_out;
  unsigned short* Wt = (unsigned short*)d_ws;  // 512*512*2 = 512 KB scratch

  wcvt_kernel<<<dim3(16, 16), dim3(32, 8), 0, stream>>>(W, Wt);
  lif_fused_kernel<<<NBLK, THREADS, 0, stream>>>(spikes, Wt, b, lnw, lnb, out);
}